// Round 3
// baseline (16.915 us; speedup 1.0000x reference)
//
#include <hip/hip_runtime.h>
#include <hip/hip_bf16.h>

// IdentityEmbedding: projection is the constant [I_1024; 0], so
//   out[row, j] = (idx[row] == j && idx[row] < 1024) ? 1.0f : 0.0f
// Pure 64 MiB streaming write (+ 64 KiB idx read).
//
// Round-3 structure: 2048 blocks x 256 threads; each block owns 8
// consecutive rows; each thread issues 8 independent float4 nontemporal
// stores (64 B/thread) to amortize dispatch ramp and give store ILP.
// Lane t owns float4 #t of each row (elements [4t, 4t+4)); the unique
// lane with (idx>>2)==t (only possible when idx < 1024) sets one
// component to 1.0.

typedef float f32x4 __attribute__((ext_vector_type(4)));

constexpr int ROWS_PER_BLOCK = 8;

__global__ void __launch_bounds__(256)
IdentityEmbedding_14147622273767_kernel(
    const int* __restrict__ idx,
    float* __restrict__ out) {
    const int t    = threadIdx.x;                      // 0 .. 255
    const int row0 = blockIdx.x * ROWS_PER_BLOCK;      // 0, 8, 16, ...

    // Block-uniform scalar loads of the 8 row indices.
    int iv[ROWS_PER_BLOCK];
#pragma unroll
    for (int r = 0; r < ROWS_PER_BLOCK; ++r) iv[r] = idx[row0 + r];

#pragma unroll
    for (int r = 0; r < ROWS_PER_BLOCK; ++r) {
        f32x4 v = {0.0f, 0.0f, 0.0f, 0.0f};
        if ((iv[r] >> 2) == t) {                       // implies iv < 1024
            v[iv[r] & 3] = 1.0f;
        }
        f32x4* __restrict__ dst =
            reinterpret_cast<f32x4*>(out + (size_t)(row0 + r) * 1024);
        __builtin_nontemporal_store(v, dst + t);
    }
}

extern "C" void kernel_launch(void* const* d_in, const int* in_sizes, int n_in,
                              void* d_out, int out_size, void* d_ws, size_t ws_size,
                              hipStream_t stream) {
    const int* idx = (const int*)d_in[0];   // (B*T,) int32
    float*     out = (float*)d_out;         // (B*T, N_EMBD) f32
    const int nrows  = in_sizes[0];         // 16384
    const int nblocks = nrows / ROWS_PER_BLOCK;  // 2048
    IdentityEmbedding_14147622273767_kernel<<<nblocks, 256, 0, stream>>>(idx, out);
}

// Round 4
// 15.486 us; speedup vs baseline: 1.0923x; 1.0923x over previous
//
#include <hip/hip_runtime.h>
#include <hip/hip_bf16.h>

// IdentityEmbedding: projection is the constant [I_1024; 0], so
//   out[row, j] = (idx[row] == j && idx[row] < 1024) ? 1.0f : 0.0f
// Pure 64 MiB streaming write (+ 64 KiB idx read).
//
// Round-4: identical to round 2 but with PLAIN (cached) stores instead of
// nontemporal. Stores retire into L2/L3 and drain overlaps the kernel
// tail; nontemporal write-around forced every store to HBM completion
// (4.1 TB/s effective vs the fill kernel's 7.1 TB/s).
//
// One 256-thread block per row (1024 f32 = 256 float4). Lane t owns
// elements [4t, 4t+4); the unique lane with (idx>>2)==t (only possible
// when idx < 1024) sets one component to 1.0.

typedef float f32x4 __attribute__((ext_vector_type(4)));

__global__ void __launch_bounds__(256)
IdentityEmbedding_14147622273767_kernel(
    const int* __restrict__ idx,
    float* __restrict__ out) {
    const int row = blockIdx.x;          // 0 .. 16383
    const int t   = threadIdx.x;         // 0 .. 255
    const int iv  = idx[row];            // block-uniform -> scalar load

    f32x4 v = {0.0f, 0.0f, 0.0f, 0.0f};
    if ((iv >> 2) == t) {                // t < 256 => implies iv < 1024
        v[iv & 3] = 1.0f;
    }

    f32x4* __restrict__ dst =
        reinterpret_cast<f32x4*>(out + (size_t)row * 1024);
    dst[t] = v;
}

extern "C" void kernel_launch(void* const* d_in, const int* in_sizes, int n_in,
                              void* d_out, int out_size, void* d_ws, size_t ws_size,
                              hipStream_t stream) {
    const int* idx = (const int*)d_in[0];   // (B*T,) int32
    float*     out = (float*)d_out;         // (B*T, N_EMBD) f32
    const int nrows = in_sizes[0];          // 16384
    IdentityEmbedding_14147622273767_kernel<<<nrows, 256, 0, stream>>>(idx, out);
}